// Round 1
// 88.346 us; speedup vs baseline: 1.1365x; 1.1365x over previous
//
#include <hip/hip_runtime.h>
#include <hip/hip_bf16.h>

#define NMAX 2048
#define HH 128
#define WW 128
#define NSEG 16
#define SEG 128            // NMAX / NSEG
#define NEARP 0.1f
#define CULL_LOG_EPS -18.0f   // keep iff max-over-tile ln(op*exp(p)) > -18

// Runtime-adaptive input load: reference ships fp32; guard against a bf16
// dataset variant. Detected from intrinsics[0] (==150.0 iff fp32; bf16-packed
// bytes read as float give a denormal ~2e-41).
static __device__ __forceinline__ float ldin(const void* p, int i, bool is32) {
    return is32 ? ((const float*)p)[i]
                : __bfloat162float(((const __hip_bfloat16*)p)[i]);
}
static __device__ __forceinline__ bool detect32(const void* intr) {
    return ((const float*)intr)[0] > 1.0f;
}
static __device__ __forceinline__ void stout(void* out, int i, float v, bool is32) {
    if (is32) ((float*)out)[i] = v;
    else      ((__hip_bfloat16*)out)[i] = __float2bfloat16(v);
}

// Record layout (12 floats, 3x float4):
// [0]=u [1]=v [2]=na(=-0.5*cA) [3]=nb(=-cB) [4]=nc(=-0.5*cC) [5]=op
// [6]=cr [7]=cg [8]=cb
// [9]=qy = nc - nb^2/(4 na)   (max over dx of power at fixed dy, coeff of dy^2)
// [10]=ln(op)                 (-inf for invalid/zero-opacity -> self-culling)
// [11]=qx = na - nb^2/(4 nc)
// pwr = na*dx^2 + nb*dx*dy + nc*dy^2   (exact same value as reference form)

// ---------------------------------------------------------------- preprocess
__global__ __launch_bounds__(256) void gs_preprocess(
    const void* __restrict__ means,
    const void* __restrict__ log_scales,
    const void* __restrict__ rots,
    const void* __restrict__ colors,
    const void* __restrict__ opac,
    const void* __restrict__ intr,
    const void* __restrict__ c2w,
    int n,
    unsigned long long* __restrict__ keys,
    float* __restrict__ params)
{
    int i = blockIdx.x * blockDim.x + threadIdx.x;
    if (i >= NMAX) return;
    bool is32 = detect32(intr);
    if (i >= n) {
        // unique key (sorts to the end, stable by index)
        keys[i] = (((unsigned long long)0x7f800000u) << 32) | (unsigned int)i;
        return;
    }

    // camera: Rwc = Rcw^T, twc = -Rwc @ tcw
    float Rwc[3][3], twc[3];
    {
        float Rcw[3][3], tcw[3];
        for (int r = 0; r < 3; ++r) {
            for (int c = 0; c < 3; ++c) Rcw[r][c] = ldin(c2w, r * 4 + c, is32);
            tcw[r] = ldin(c2w, r * 4 + 3, is32);
        }
        for (int r = 0; r < 3; ++r)
            for (int c = 0; c < 3; ++c) Rwc[r][c] = Rcw[c][r];
        for (int r = 0; r < 3; ++r)
            twc[r] = -(Rwc[r][0] * tcw[0] + Rwc[r][1] * tcw[1] + Rwc[r][2] * tcw[2]);
    }
    float fx = ldin(intr, 0, is32), fy = ldin(intr, 4, is32);
    float cx = ldin(intr, 2, is32), cy = ldin(intr, 5, is32);

    float mx = ldin(means, 3 * i, is32), my = ldin(means, 3 * i + 1, is32),
          mz = ldin(means, 3 * i + 2, is32);
    float px = Rwc[0][0] * mx + Rwc[0][1] * my + Rwc[0][2] * mz + twc[0];
    float py = Rwc[1][0] * mx + Rwc[1][1] * my + Rwc[1][2] * mz + twc[1];
    float pz = Rwc[2][0] * mx + Rwc[2][1] * my + Rwc[2][2] * mz + twc[2];
    bool valid = pz > NEARP;
    float zc = fmaxf(pz, NEARP);
    float izc = 1.0f / zc;
    float u = fx * px * izc + cx;
    float v = fy * py * izc + cy;

    // quaternion -> R
    float qw = ldin(rots, 4 * i, is32), qx = ldin(rots, 4 * i + 1, is32),
          qy = ldin(rots, 4 * i + 2, is32), qz = ldin(rots, 4 * i + 3, is32);
    float nrm = sqrtf(qw * qw + qx * qx + qy * qy + qz * qz);
    float inv = 1.0f / fmaxf(nrm, 1e-8f);
    qw *= inv; qx *= inv; qy *= inv; qz *= inv;
    float xx = qx * qx, yy = qy * qy, zz = qz * qz;
    float xy = qx * qy, xz = qx * qz, yz = qy * qz;
    float wx = qw * qx, wy = qw * qy, wz = qw * qz;
    float R[3][3] = {
        {1.f - 2.f * (yy + zz), 2.f * (xy - wz),       2.f * (xz + wy)},
        {2.f * (xy + wz),       1.f - 2.f * (xx + zz), 2.f * (yz - wx)},
        {2.f * (xz - wy),       2.f * (yz + wx),       1.f - 2.f * (xx + yy)}
    };
    float s2[3];
    for (int k = 0; k < 3; ++k) s2[k] = __expf(2.0f * ldin(log_scales, 3 * i + k, is32));

    // cov3d = R diag(s2) R^T + 1e-6 I
    float M[3][3];
    for (int r = 0; r < 3; ++r)
        for (int c = 0; c < 3; ++c)
            M[r][c] = R[r][0] * s2[0] * R[c][0] + R[r][1] * s2[1] * R[c][1]
                    + R[r][2] * s2[2] * R[c][2];
    M[0][0] += 1e-6f; M[1][1] += 1e-6f; M[2][2] += 1e-6f;

    // cov_cam = Rwc M Rwc^T
    float TM[3][3];
    for (int r = 0; r < 3; ++r)
        for (int c = 0; c < 3; ++c)
            TM[r][c] = Rwc[r][0] * M[0][c] + Rwc[r][1] * M[1][c] + Rwc[r][2] * M[2][c];
    float CC[3][3];
    for (int r = 0; r < 3; ++r)
        for (int c = 0; c < 3; ++c)
            CC[r][c] = TM[r][0] * Rwc[c][0] + TM[r][1] * Rwc[c][1] + TM[r][2] * Rwc[c][2];

    // J rows
    float J0[3] = {fx * izc, 0.0f, -fx * px * izc * izc};
    float J1[3] = {0.0f, fy * izc, -fy * py * izc * izc};
    float t0[3], t1[3];
    for (int c = 0; c < 3; ++c) {
        t0[c] = J0[0] * CC[0][c] + J0[1] * CC[1][c] + J0[2] * CC[2][c];
        t1[c] = J1[0] * CC[0][c] + J1[1] * CC[1][c] + J1[2] * CC[2][c];
    }
    float a  = t0[0] * J0[0] + t0[1] * J0[1] + t0[2] * J0[2] + 0.3f;
    float bq = t0[0] * J1[0] + t0[1] * J1[1] + t0[2] * J1[2];
    float cq = t1[0] * J1[0] + t1[1] * J1[1] + t1[2] * J1[2] + 0.3f;
    float det = fmaxf(a * cq - bq * bq, 1e-12f);
    float idet = 1.0f / det;
    float cA = cq * idet, cB = -bq * idet, cCc = a * idet;

    float o  = ldin(opac, i, is32);
    float op = valid ? (1.0f / (1.0f + __expf(-o))) : 0.0f;
    float cr = fminf(fmaxf(ldin(colors, 3 * i, is32), 0.f), 1.f);
    float cg = fminf(fmaxf(ldin(colors, 3 * i + 1, is32), 0.f), 1.f);
    float cb = fminf(fmaxf(ldin(colors, 3 * i + 2, is32), 0.f), 1.f);

    float zkey = valid ? zc : __builtin_inff();
    keys[i] = (((unsigned long long)__float_as_uint(zkey)) << 32) | (unsigned int)i;

    // conic coefficients for the power form p = na dx^2 + nb dx dy + nc dy^2
    float na  = -0.5f * cA;   // < 0 (conic negative-definite: cA,cC>0, det>0)
    float nb  = -cB;
    float ncc = -0.5f * cCc;  // < 0
    // tile-cull helpers: max over unconstrained other-axis of the quadratic
    float qyb = ncc - nb * nb / (4.0f * na);   // coeff of dy^2, <= 0
    float qxb = na  - nb * nb / (4.0f * ncc);  // coeff of dx^2, <= 0
    float lnop = __logf(op);                   // -inf when op==0 (invalid)

    float* p = params + i * 12;
    p[0] = u;  p[1] = v;
    p[2] = na;  p[3] = nb;  p[4] = ncc;
    p[5] = op;
    p[6] = cr; p[7] = cg; p[8] = cb;
    p[9] = qyb; p[10] = lnop; p[11] = qxb;
}

// ------------------------------- rank-by-count (stable, unique keys) + scatter
// 64 blocks x 256 threads; block handles 32 gaussians, each split into 8
// interleaved key-chunks (j = c mod 8) so a wave reads 8 consecutive u64
// (conflict-free, 8-lane broadcast groups). One barrier pair; cooperative
// float4 scatter. Unique keys ((depth_bits<<32)|idx) => rank == stable argsort.
__global__ __launch_bounds__(256) void gs_rank_scatter(
    const unsigned long long* __restrict__ keys_in,
    const float* __restrict__ params_in,
    float* __restrict__ params_sorted,
    int n)
{
    __shared__ unsigned long long sk[NMAX];
    __shared__ int pr[32][9];   // +1 pad
    __shared__ int rk[32];
    int t = threadIdx.x;
    #pragma unroll
    for (int e = 0; e < 8; ++e) sk[t + e * 256] = keys_in[t + e * 256];
    __syncthreads();

    int g0 = blockIdx.x * 32;
    int gi = t >> 3;   // 0..31
    int c  = t & 7;    // chunk phase
    unsigned long long mykey = sk[g0 + gi];
    int cnt = 0;
    #pragma unroll 8
    for (int j = c; j < NMAX; j += 8)
        cnt += (sk[j] < mykey) ? 1 : 0;
    pr[gi][c] = cnt;
    __syncthreads();

    if (t < 32) {
        int r = 0;
        #pragma unroll
        for (int k = 0; k < 8; ++k) r += pr[t][k];
        rk[t] = r;
    }
    __syncthreads();

    if (t < 96) {
        int g = t / 3, q = t % 3;
        int src = g0 + g;
        float4 val;
        if (src < n) val = ((const float4*)params_in)[src * 3 + q];
        else         val = make_float4(0.f, 0.f, 0.f, 0.f);
        ((float4*)params_sorted)[rk[g] * 3 + q] = val;
    }
}

// ------------------------------------------- render (tiled + culled, 2 px/th)
// Grid: (32 tiles of 32x16 px, NSEG segments). Per block: stage its segment's
// SEG gaussians (threads 0..SEG-1, one each), conservatively cull against the
// tile via min(qy*dym^2, qx*dxm^2) + ln(op) > CULL_LOG_EPS (exact upper bound
// on ln(alpha) over the tile; conic is negative-definite so each single-axis
// bound maximizes the other axis in closed form), compact in depth order via
// ballot prefix-sum, then composite only the survivors.
__global__ __launch_bounds__(256) void gs_render(
    const float* __restrict__ params_sorted,
    float4* __restrict__ segbuf)
{
    __shared__ float sp[SEG * 12];
    __shared__ int swcnt[2];
    int seg = blockIdx.y;
    int t = threadIdx.x;
    int x0 = (blockIdx.x & 3) * 32;     // tile origin
    int y0 = (blockIdx.x >> 2) * 16;

    // ---- stage + cull (threads 0..SEG-1 own one gaussian each)
    float4 a4, b4, c4;
    bool keep = false;
    if (t < SEG) {
        const float4* src = (const float4*)(params_sorted + (seg * SEG + t) * 12);
        a4 = src[0];   // u v na nb
        b4 = src[1];   // nc op cr cg
        c4 = src[2];   // cb qy lnop qx
        float dxm = fmaxf(fmaxf((float)x0 - a4.x, a4.x - (float)(x0 + 31)), 0.0f);
        float dym = fmaxf(fmaxf((float)y0 - a4.y, a4.y - (float)(y0 + 15)), 0.0f);
        float bound = fminf(c4.y * dym * dym, c4.w * dxm * dxm) + c4.z;
        keep = (bound > CULL_LOG_EPS) && (b4.y > 0.0f);
    }
    unsigned long long ball = __ballot(keep);
    int lane = t & 63, wid = t >> 6;
    if (lane == 0 && wid < 2) swcnt[wid] = (int)__popcll(ball);
    __syncthreads();
    int M = swcnt[0] + swcnt[1];
    if (keep) {
        int rank = (wid ? swcnt[0] : 0)
                 + (int)__popcll(ball & ((1ull << lane) - 1ull));
        float4* d = (float4*)(sp + rank * 12);
        d[0] = a4; d[1] = b4; d[2] = c4;
    }
    __syncthreads();

    // ---- composite 2 adjacent columns per thread
    int col = x0 + ((t & 15) << 1);
    int row = y0 + (t >> 4);
    float px0 = (float)col;
    float px1 = px0 + 1.0f;
    float py  = (float)row;
    int pid0 = row * WW + col;

    float T0 = 1.f, r0 = 0.f, g0 = 0.f, b0 = 0.f;
    float T1 = 1.f, r1 = 0.f, g1 = 0.f, b1 = 0.f;
    #pragma unroll 2
    for (int i = 0; i < M; ++i) {
        const float* gp = sp + i * 12;
        float4 A = *(const float4*)(gp);        // u v na nb
        float4 B = *(const float4*)(gp + 4);    // nc op cr cg
        float4 C = *(const float4*)(gp + 8);    // cb qy lnop qx
        float dy    = py - A.y;
        float nbdy  = A.w * dy;
        float ncdy2 = (B.x * dy) * dy;

        float dx0 = px0 - A.x;
        float p0 = fmaf(fmaf(A.z, dx0, nbdy), dx0, ncdy2);
        p0 = fminf(p0, 0.0f);
        float al0 = fminf(B.y * __expf(p0), 0.99f);
        float w0 = al0 * T0;
        r0 = fmaf(w0, B.z, r0);
        g0 = fmaf(w0, B.w, g0);
        b0 = fmaf(w0, C.x, b0);
        T0 *= (1.0f - al0);

        float dx1 = px1 - A.x;
        float p1 = fmaf(fmaf(A.z, dx1, nbdy), dx1, ncdy2);
        p1 = fminf(p1, 0.0f);
        float al1 = fminf(B.y * __expf(p1), 0.99f);
        float w1 = al1 * T1;
        r1 = fmaf(w1, B.z, r1);
        g1 = fmaf(w1, B.w, g1);
        b1 = fmaf(w1, C.x, b1);
        T1 *= (1.0f - al1);
    }
    segbuf[seg * (HH * WW) + pid0]     = make_float4(r0, g0, b0, T0);
    segbuf[seg * (HH * WW) + pid0 + 1] = make_float4(r1, g1, b1, T1);
}

// ---------------------------------------------------------------- combine
__global__ __launch_bounds__(256) void gs_combine(
    const float4* __restrict__ segbuf,
    void* __restrict__ out,
    const void* __restrict__ intr)
{
    int pid = blockIdx.x * 256 + threadIdx.x;
    if (pid >= HH * WW) return;
    bool is32 = detect32(intr);
    float r = 0.f, g = 0.f, b = 0.f, T = 1.0f;
    #pragma unroll
    for (int s = 0; s < NSEG; ++s) {
        float4 vv = segbuf[s * (HH * WW) + pid];
        r = fmaf(T, vv.x, r);
        g = fmaf(T, vv.y, g);
        b = fmaf(T, vv.z, b);
        T *= vv.w;
    }
    stout(out, pid * 3 + 0, r, is32);
    stout(out, pid * 3 + 1, g, is32);
    stout(out, pid * 3 + 2, b, is32);
}

// -------------------------------- fallback: fused render over all gaussians
// (used only if ws_size can't hold the segment buffer)
__global__ __launch_bounds__(256) void gs_render_all(
    const float* __restrict__ params_sorted,
    void* __restrict__ out,
    const void* __restrict__ intr)
{
    __shared__ float sp[SEG * 12];
    int t = threadIdx.x;
    int pid = blockIdx.x * 256 + t;
    bool is32 = detect32(intr);
    float pxf = (float)(pid & (WW - 1));
    float pyf = (float)(pid >> 7);

    float T = 1.f, r = 0.f, g = 0.f, b = 0.f;
    for (int seg = 0; seg < NSEG; ++seg) {
        __syncthreads();
        const float4* src = (const float4*)(params_sorted + seg * SEG * 12);
        float4* dst = (float4*)sp;
        #pragma unroll
        for (int k = t; k < SEG * 3; k += 256) dst[k] = src[k];
        __syncthreads();
        for (int i = 0; i < SEG; ++i) {
            const float* gp = sp + i * 12;
            float dx = pxf - gp[0];
            float dy = pyf - gp[1];
            float pwr = fmaf(fmaf(gp[2], dx, gp[3] * dy), dx, (gp[4] * dy) * dy);
            pwr = fminf(pwr, 0.0f);
            float alpha = fminf(gp[5] * __expf(pwr), 0.99f);
            float wgt = alpha * T;
            r = fmaf(wgt, gp[6], r);
            g = fmaf(wgt, gp[7], g);
            b = fmaf(wgt, gp[8], b);
            T *= (1.0f - alpha);
        }
    }
    stout(out, pid * 3 + 0, r, is32);
    stout(out, pid * 3 + 1, g, is32);
    stout(out, pid * 3 + 2, b, is32);
}

extern "C" void kernel_launch(void* const* d_in, const int* in_sizes, int n_in,
                              void* d_out, int out_size, void* d_ws, size_t ws_size,
                              hipStream_t stream)
{
    const void* means      = d_in[0];
    const void* log_scales = d_in[1];
    const void* rotations  = d_in[2];
    const void* colors     = d_in[3];
    const void* opacities  = d_in[4];
    const void* intrinsics = d_in[5];
    const void* cam2world  = d_in[6];

    int n = in_sizes[4];
    if (n > NMAX) n = NMAX;

    // workspace layout
    size_t off_keys   = 0;                       // 16 KB
    size_t off_params = NMAX * 8;                // 96 KB
    size_t off_sorted = off_params + NMAX * 48;  // 96 KB
    size_t off_seg    = off_sorted + NMAX * 48;  // 4 MB
    size_t need_seg   = off_seg + (size_t)NSEG * HH * WW * 16;

    unsigned long long* keys = (unsigned long long*)((char*)d_ws + off_keys);
    float* params  = (float*)((char*)d_ws + off_params);
    float* sortedp = (float*)((char*)d_ws + off_sorted);
    float4* segbuf = (float4*)((char*)d_ws + off_seg);

    gs_preprocess<<<NMAX / 256, 256, 0, stream>>>(
        means, log_scales, rotations, colors, opacities, intrinsics, cam2world,
        n, keys, params);
    gs_rank_scatter<<<NMAX / 32, 256, 0, stream>>>(keys, params, sortedp, n);

    if (ws_size >= need_seg) {
        dim3 rg(32, NSEG);   // 32x16-px tiles x NSEG segments
        gs_render<<<rg, 256, 0, stream>>>(sortedp, segbuf);
        gs_combine<<<HH * WW / 256, 256, 0, stream>>>(segbuf, d_out, intrinsics);
    } else {
        gs_render_all<<<HH * WW / 256, 256, 0, stream>>>(sortedp, d_out, intrinsics);
    }
}